// Round 1
// baseline (4166.120 us; speedup 1.0000x reference)
//
#include <hip/hip_runtime.h>

#define NN0 600000
#define NN1 100000
#define NN2 20000
#define NN3 4096
#define EE0 1500000
#define EE1 200000
#define EE2 40960
#define DIN 100
#define DH  256
#define DOUT 47

// ---------------- scatter (gather rows, atomic segment-sum + count) ----------

// Layer 0: D_IN=100 floats = 25 float4 per edge. Work item = (edge, float4-chunk).
__global__ void scatter_l0(const float* __restrict__ x,
                           const int* __restrict__ src,
                           const int* __restrict__ dst,
                           float* __restrict__ agg, float* __restrict__ cnt) {
    const long long total = (long long)EE0 * 25;
    for (long long t = (long long)blockIdx.x * blockDim.x + threadIdx.x;
         t < total; t += (long long)gridDim.x * blockDim.x) {
        int e = (int)(t / 25);
        int c = (int)(t % 25);
        int s = src[e], d = dst[e];
        const float4 v = *reinterpret_cast<const float4*>(x + (long long)s * DIN + c * 4);
        float* p = agg + (long long)d * DIN + c * 4;
        atomicAdd(p + 0, v.x);
        atomicAdd(p + 1, v.y);
        atomicAdd(p + 2, v.z);
        atomicAdd(p + 3, v.w);
        if (c == 0) atomicAdd(cnt + d, 1.0f);
    }
}

// Layers 1/2: D=256 floats = 64 float4 per edge.
__global__ void scatter_256(const float* __restrict__ h,
                            const int* __restrict__ src,
                            const int* __restrict__ dst,
                            float* __restrict__ agg, float* __restrict__ cnt, int E) {
    const long long total = (long long)E * 64;
    for (long long t = (long long)blockIdx.x * blockDim.x + threadIdx.x;
         t < total; t += (long long)gridDim.x * blockDim.x) {
        int e = (int)(t >> 6);
        int c = (int)(t & 63);
        int s = src[e], d = dst[e];
        const float4 v = *reinterpret_cast<const float4*>(h + (long long)s * DH + c * 4);
        float* p = agg + (long long)d * DH + c * 4;
        atomicAdd(p + 0, v.x);
        atomicAdd(p + 1, v.y);
        atomicAdd(p + 2, v.z);
        atomicAdd(p + 3, v.w);
        if (c == 0) atomicAdd(cnt + d, 1.0f);
    }
}

__global__ void inv_cnt_kernel(float* cnt, int n) {
    int i = blockIdx.x * blockDim.x + threadIdx.x;
    if (i < n) cnt[i] = 1.0f / fmaxf(cnt[i], 1.0f);
}

// ---------------- dual GEMM: C = (A1 * scl[row]) @ B1 + A2 @ B2 + bias -------
// A1, A2: [M,K] row-major. B1, B2: [K,N] row-major. scl applied to A1 only.
template <int RELU>
__global__ __launch_bounds__(256)
void dual_gemm(const float* __restrict__ A1, const float* __restrict__ scl,
               const float* __restrict__ A2,
               const float* __restrict__ B1, const float* __restrict__ B2,
               const float* __restrict__ bias, float* __restrict__ C,
               int M, int N, int K) {
    const int BM = 64, BN = 64, BK = 32;
    __shared__ float As[BK][BM + 1];
    __shared__ float Bs[BK][BN];

    const int tid = threadIdx.x;
    const int tx = tid & 15;        // 0..15 -> cols
    const int ty = tid >> 4;        // 0..15 -> rows
    const int m0 = blockIdx.y * BM;
    const int n0 = blockIdx.x * BN;

    float acc[4][4] = {};

    for (int pass = 0; pass < 2; ++pass) {
        const float* A = pass ? A2 : A1;
        const float* B = pass ? B2 : B1;
        const bool use_scl = (pass == 0) && (scl != nullptr);

        for (int k0 = 0; k0 < K; k0 += BK) {
            // A tile: BM x BK = 2048 elems, 8 per thread; consecutive tid -> consecutive k
            #pragma unroll
            for (int i = 0; i < 8; ++i) {
                int l = tid + i * 256;
                int mi = l >> 5;
                int kk = l & 31;
                int row = m0 + mi, k = k0 + kk;
                float v = 0.0f;
                if (row < M && k < K) {
                    v = A[(long long)row * K + k];
                    if (use_scl) v *= scl[row];
                }
                As[kk][mi] = v;
            }
            // B tile: BK x BN = 2048 elems
            #pragma unroll
            for (int i = 0; i < 8; ++i) {
                int l = tid + i * 256;
                int kk = l >> 6;
                int nn = l & 63;
                int k = k0 + kk, col = n0 + nn;
                float v = 0.0f;
                if (k < K && col < N) v = B[(long long)k * N + col];
                Bs[kk][nn] = v;
            }
            __syncthreads();

            #pragma unroll
            for (int kk = 0; kk < BK; ++kk) {
                float a[4], b[4];
                #pragma unroll
                for (int i = 0; i < 4; ++i) a[i] = As[kk][ty * 4 + i];
                #pragma unroll
                for (int j = 0; j < 4; ++j) b[j] = Bs[kk][tx * 4 + j];
                #pragma unroll
                for (int i = 0; i < 4; ++i)
                    #pragma unroll
                    for (int j = 0; j < 4; ++j)
                        acc[i][j] += a[i] * b[j];
            }
            __syncthreads();
        }
    }

    #pragma unroll
    for (int i = 0; i < 4; ++i) {
        int row = m0 + ty * 4 + i;
        if (row >= M) continue;
        #pragma unroll
        for (int j = 0; j < 4; ++j) {
            int col = n0 + tx * 4 + j;
            if (col >= N) continue;
            float v = acc[i][j] + bias[col];
            if (RELU) v = fmaxf(v, 0.0f);
            C[(long long)row * N + col] = v;
        }
    }
}

// ---------------- log_softmax over 47 classes, one wave per row --------------
__global__ void log_softmax_47(const float* __restrict__ z, float* __restrict__ out) {
    int row = blockIdx.x;
    int lane = threadIdx.x;  // 64 lanes
    float v = (lane < DOUT) ? z[(long long)row * DOUT + lane] : -INFINITY;
    float m = v;
    #pragma unroll
    for (int off = 32; off; off >>= 1) m = fmaxf(m, __shfl_xor(m, off));
    float e = (lane < DOUT) ? __expf(v - m) : 0.0f;
    // use precise expf to be safe
    e = (lane < DOUT) ? expf(v - m) : 0.0f;
    float s = e;
    #pragma unroll
    for (int off = 32; off; off >>= 1) s += __shfl_xor(s, off);
    if (lane < DOUT) out[(long long)row * DOUT + lane] = v - m - logf(s);
}

// ---------------- launch ------------------------------------------------------
extern "C" void kernel_launch(void* const* d_in, const int* in_sizes, int n_in,
                              void* d_out, int out_size, void* d_ws, size_t ws_size,
                              hipStream_t stream) {
    const float* x   = (const float*)d_in[0];
    const int* e0s   = (const int*)d_in[1];
    const int* e0d   = (const int*)d_in[2];
    const int* e1s   = (const int*)d_in[3];
    const int* e1d   = (const int*)d_in[4];
    const int* e2s   = (const int*)d_in[5];
    const int* e2d   = (const int*)d_in[6];
    const float* Wl0 = (const float*)d_in[7];
    const float* Wr0 = (const float*)d_in[8];
    const float* b0  = (const float*)d_in[9];
    const float* Wl1 = (const float*)d_in[10];
    const float* Wr1 = (const float*)d_in[11];
    const float* b1  = (const float*)d_in[12];
    const float* Wl2 = (const float*)d_in[13];
    const float* Wr2 = (const float*)d_in[14];
    const float* b2  = (const float*)d_in[15];

    char* ws = (char*)d_ws;
    size_t off = 0;
    auto alloc = [&](size_t bytes) -> void* {
        void* p = ws + off;
        off += (bytes + 255) & ~(size_t)255;
        return p;
    };
    float* agg0 = (float*)alloc((size_t)NN1 * DIN * 4);   // 40 MB
    float* cnt0 = (float*)alloc((size_t)NN1 * 4);
    float* h1   = (float*)alloc((size_t)NN1 * DH * 4);    // 102.4 MB
    float* agg1 = (float*)alloc((size_t)NN2 * DH * 4);    // 20.5 MB
    float* cnt1 = (float*)alloc((size_t)NN2 * 4);
    float* h2   = (float*)alloc((size_t)NN2 * DH * 4);    // 20.5 MB
    float* agg2 = (float*)alloc((size_t)NN3 * DH * 4);    // 4 MB
    float* cnt2 = (float*)alloc((size_t)NN3 * 4);
    float* z    = (float*)alloc((size_t)NN3 * DOUT * 4);  // 0.77 MB

    // zero the accumulation buffers (every call; ws is not re-poisoned but we
    // must not rely on leftover state)
    hipMemsetAsync(agg0, 0, (size_t)NN1 * DIN * 4, stream);
    hipMemsetAsync(cnt0, 0, (size_t)NN1 * 4, stream);
    hipMemsetAsync(agg1, 0, (size_t)NN2 * DH * 4, stream);
    hipMemsetAsync(cnt1, 0, (size_t)NN2 * 4, stream);
    hipMemsetAsync(agg2, 0, (size_t)NN3 * DH * 4, stream);
    hipMemsetAsync(cnt2, 0, (size_t)NN3 * 4, stream);

    // ---- layer 0 ----
    scatter_l0<<<2048, 256, 0, stream>>>(x, e0s, e0d, agg0, cnt0);
    inv_cnt_kernel<<<(NN1 + 255) / 256, 256, 0, stream>>>(cnt0, NN1);
    {
        dim3 grid((DH + 63) / 64, (NN1 + 63) / 64);
        dual_gemm<1><<<grid, 256, 0, stream>>>(agg0, cnt0, x, Wl0, Wr0, b0, h1,
                                               NN1, DH, DIN);
    }

    // ---- layer 1 ----
    scatter_256<<<2048, 256, 0, stream>>>(h1, e1s, e1d, agg1, cnt1, EE1);
    inv_cnt_kernel<<<(NN2 + 255) / 256, 256, 0, stream>>>(cnt1, NN2);
    {
        dim3 grid((DH + 63) / 64, (NN2 + 63) / 64);
        dual_gemm<1><<<grid, 256, 0, stream>>>(agg1, cnt1, h1, Wl1, Wr1, b1, h2,
                                               NN2, DH, DH);
    }

    // ---- layer 2 ----
    scatter_256<<<1024, 256, 0, stream>>>(h2, e2s, e2d, agg2, cnt2, EE2);
    inv_cnt_kernel<<<(NN3 + 255) / 256, 256, 0, stream>>>(cnt2, NN3);
    {
        dim3 grid((DOUT + 63) / 64, (NN3 + 63) / 64);
        dual_gemm<0><<<grid, 256, 0, stream>>>(agg2, cnt2, h2, Wl2, Wr2, b2, z,
                                               NN3, DOUT, DH);
    }

    // ---- log_softmax ----
    log_softmax_47<<<NN3, 64, 0, stream>>>(z, (float*)d_out);
}

// Round 2
// 1411.243 us; speedup vs baseline: 2.9521x; 2.9521x over previous
//
#include <hip/hip_runtime.h>

#define NN0 600000
#define NN1 100000
#define NN2 20000
#define NN3 4096
#define EE0 1500000
#define EE1 200000
#define EE2 40960
#define DIN 100
#define DH  256
#define DOUT 47

// ================= CSR build =================================================

__global__ void hist_kernel(const int* __restrict__ dst, int E, int* __restrict__ cnt) {
    for (int e = blockIdx.x * blockDim.x + threadIdx.x; e < E;
         e += gridDim.x * blockDim.x)
        atomicAdd(&cnt[dst[e]], 1);
}

// scan pass 1: per-block (1024 items) sums
__global__ void scan1(const int* __restrict__ cnt, int n, int* __restrict__ part) {
    __shared__ int s[256];
    int base = blockIdx.x * 1024;
    int sum = 0;
    for (int i = threadIdx.x; i < 1024; i += 256) {
        int idx = base + i;
        sum += (idx < n) ? cnt[idx] : 0;
    }
    s[threadIdx.x] = sum;
    __syncthreads();
    for (int off = 128; off; off >>= 1) {
        if (threadIdx.x < off) s[threadIdx.x] += s[threadIdx.x + off];
        __syncthreads();
    }
    if (threadIdx.x == 0) part[blockIdx.x] = s[0];
}

// scan pass 2: serial exclusive scan of block partials (nb <= 128)
__global__ void scan2(int* part, int nb) {
    if (threadIdx.x == 0 && blockIdx.x == 0) {
        int run = 0;
        for (int i = 0; i < nb; ++i) { int v = part[i]; part[i] = run; run += v; }
    }
}

// scan pass 3: per-block exclusive scan, add partial offset, emit row_ptr+cursor
__global__ void scan3(const int* __restrict__ cnt, int n, const int* __restrict__ part,
                      int* __restrict__ row_ptr, int* __restrict__ cursor) {
    __shared__ int s[256];
    int base = blockIdx.x * 1024;
    int v[4];
    int sum = 0;
    #pragma unroll
    for (int j = 0; j < 4; ++j) {
        int idx = base + threadIdx.x * 4 + j;
        v[j] = (idx < n) ? cnt[idx] : 0;
        sum += v[j];
    }
    s[threadIdx.x] = sum;
    __syncthreads();
    // Hillis-Steele inclusive scan
    for (int off = 1; off < 256; off <<= 1) {
        int t = (threadIdx.x >= off) ? s[threadIdx.x - off] : 0;
        __syncthreads();
        s[threadIdx.x] += t;
        __syncthreads();
    }
    int off0 = part[blockIdx.x] + s[threadIdx.x] - sum;  // exclusive base for thread
    #pragma unroll
    for (int j = 0; j < 4; ++j) {
        int idx = base + threadIdx.x * 4 + j;
        if (idx < n) {
            row_ptr[idx] = off0;
            cursor[idx]  = off0;
            off0 += v[j];
            if (idx == n - 1) row_ptr[n] = off0;
        }
    }
}

__global__ void build_eidx(const int* __restrict__ src, const int* __restrict__ dst,
                           int E, int* __restrict__ cursor, int* __restrict__ eidx) {
    for (int e = blockIdx.x * blockDim.x + threadIdx.x; e < E;
         e += gridDim.x * blockDim.x) {
        int pos = atomicAdd(&cursor[dst[e]], 1);
        eidx[pos] = src[e];
    }
}

// ================= pull aggregation (mean folded in) =========================

// D=100: one node per block of 128 threads; thread t owns feature t.
__global__ __launch_bounds__(128)
void agg_mean_100(const float* __restrict__ x, const int* __restrict__ row_ptr,
                  const int* __restrict__ eidx, float* __restrict__ out) {
    int d = blockIdx.x;
    int t = threadIdx.x;
    int beg = row_ptr[d], end = row_ptr[d + 1];
    float a = 0.0f;
    int j = beg;
    for (; j + 1 < end; j += 2) {
        int s0 = eidx[j], s1 = eidx[j + 1];
        if (t < DIN) {
            float v0 = x[(long long)s0 * DIN + t];
            float v1 = x[(long long)s1 * DIN + t];
            a += v0 + v1;
        }
    }
    if (j < end) {
        int s0 = eidx[j];
        if (t < DIN) a += x[(long long)s0 * DIN + t];
    }
    float inv = 1.0f / fmaxf((float)(end - beg), 1.0f);
    if (t < DIN) out[(long long)d * DIN + t] = a * inv;
}

// D=256: one node per block of 256 threads.
__global__ __launch_bounds__(256)
void agg_mean_256(const float* __restrict__ h, const int* __restrict__ row_ptr,
                  const int* __restrict__ eidx, float* __restrict__ out) {
    int d = blockIdx.x;
    int t = threadIdx.x;
    int beg = row_ptr[d], end = row_ptr[d + 1];
    float a = 0.0f;
    int j = beg;
    for (; j + 1 < end; j += 2) {
        int s0 = eidx[j], s1 = eidx[j + 1];
        a += h[(long long)s0 * DH + t] + h[(long long)s1 * DH + t];
    }
    if (j < end) a += h[(long long)eidx[j] * DH + t];
    float inv = 1.0f / fmaxf((float)(end - beg), 1.0f);
    out[(long long)d * DH + t] = a * inv;
}

// ================= dual GEMM: C = A1 @ B1 + A2 @ B2 + bias ==================
template <int RELU>
__global__ __launch_bounds__(256)
void dual_gemm(const float* __restrict__ A1, const float* __restrict__ A2,
               const float* __restrict__ B1, const float* __restrict__ B2,
               const float* __restrict__ bias, float* __restrict__ C,
               int M, int N, int K) {
    const int BM = 64, BN = 64, BK = 32;
    __shared__ float As[BK][BM + 1];
    __shared__ float Bs[BK][BN];

    const int tid = threadIdx.x;
    const int tx = tid & 15;
    const int ty = tid >> 4;
    const int m0 = blockIdx.y * BM;
    const int n0 = blockIdx.x * BN;

    float acc[4][4] = {};

    for (int pass = 0; pass < 2; ++pass) {
        const float* A = pass ? A2 : A1;
        const float* B = pass ? B2 : B1;

        for (int k0 = 0; k0 < K; k0 += BK) {
            #pragma unroll
            for (int i = 0; i < 8; ++i) {
                int l = tid + i * 256;
                int mi = l >> 5;
                int kk = l & 31;
                int row = m0 + mi, k = k0 + kk;
                float v = 0.0f;
                if (row < M && k < K) v = A[(long long)row * K + k];
                As[kk][mi] = v;
            }
            #pragma unroll
            for (int i = 0; i < 8; ++i) {
                int l = tid + i * 256;
                int kk = l >> 6;
                int nn = l & 63;
                int k = k0 + kk, col = n0 + nn;
                float v = 0.0f;
                if (k < K && col < N) v = B[(long long)k * N + col];
                Bs[kk][nn] = v;
            }
            __syncthreads();

            #pragma unroll
            for (int kk = 0; kk < BK; ++kk) {
                float a[4], b[4];
                #pragma unroll
                for (int i = 0; i < 4; ++i) a[i] = As[kk][ty * 4 + i];
                #pragma unroll
                for (int j = 0; j < 4; ++j) b[j] = Bs[kk][tx * 4 + j];
                #pragma unroll
                for (int i = 0; i < 4; ++i)
                    #pragma unroll
                    for (int j = 0; j < 4; ++j)
                        acc[i][j] += a[i] * b[j];
            }
            __syncthreads();
        }
    }

    #pragma unroll
    for (int i = 0; i < 4; ++i) {
        int row = m0 + ty * 4 + i;
        if (row >= M) continue;
        #pragma unroll
        for (int j = 0; j < 4; ++j) {
            int col = n0 + tx * 4 + j;
            if (col >= N) continue;
            float v = acc[i][j] + bias[col];
            if (RELU) v = fmaxf(v, 0.0f);
            C[(long long)row * N + col] = v;
        }
    }
}

// ================= log_softmax over 47 classes ==============================
__global__ void log_softmax_47(const float* __restrict__ z, float* __restrict__ out) {
    int row = blockIdx.x;
    int lane = threadIdx.x;
    float v = (lane < DOUT) ? z[(long long)row * DOUT + lane] : -INFINITY;
    float m = v;
    #pragma unroll
    for (int off = 32; off; off >>= 1) m = fmaxf(m, __shfl_xor(m, off));
    float e = (lane < DOUT) ? expf(v - m) : 0.0f;
    float s = e;
    #pragma unroll
    for (int off = 32; off; off >>= 1) s += __shfl_xor(s, off);
    if (lane < DOUT) out[(long long)row * DOUT + lane] = v - m - logf(s);
}

// ================= launch ====================================================
static void build_csr(const int* src, const int* dst, int E, int n,
                      int* cnt, int* part, int* row_ptr, int* cursor, int* eidx,
                      hipStream_t stream) {
    hipMemsetAsync(cnt, 0, (size_t)n * 4, stream);
    hist_kernel<<<1024, 256, 0, stream>>>(dst, E, cnt);
    int nb = (n + 1023) / 1024;
    scan1<<<nb, 256, 0, stream>>>(cnt, n, part);
    scan2<<<1, 64, 0, stream>>>(part, nb);
    scan3<<<nb, 256, 0, stream>>>(cnt, n, part, row_ptr, cursor);
    build_eidx<<<1024, 256, 0, stream>>>(src, dst, E, cursor, eidx);
}

extern "C" void kernel_launch(void* const* d_in, const int* in_sizes, int n_in,
                              void* d_out, int out_size, void* d_ws, size_t ws_size,
                              hipStream_t stream) {
    const float* x   = (const float*)d_in[0];
    const int* e0s   = (const int*)d_in[1];
    const int* e0d   = (const int*)d_in[2];
    const int* e1s   = (const int*)d_in[3];
    const int* e1d   = (const int*)d_in[4];
    const int* e2s   = (const int*)d_in[5];
    const int* e2d   = (const int*)d_in[6];
    const float* Wl0 = (const float*)d_in[7];
    const float* Wr0 = (const float*)d_in[8];
    const float* b0  = (const float*)d_in[9];
    const float* Wl1 = (const float*)d_in[10];
    const float* Wr1 = (const float*)d_in[11];
    const float* b1  = (const float*)d_in[12];
    const float* Wl2 = (const float*)d_in[13];
    const float* Wr2 = (const float*)d_in[14];
    const float* b2  = (const float*)d_in[15];

    char* ws = (char*)d_ws;
    size_t off = 0;
    auto alloc = [&](size_t bytes) -> void* {
        void* p = ws + off;
        off += (bytes + 255) & ~(size_t)255;
        return p;
    };
    float* agg0 = (float*)alloc((size_t)NN1 * DIN * 4);
    float* h1   = (float*)alloc((size_t)NN1 * DH * 4);
    float* agg1 = (float*)alloc((size_t)NN2 * DH * 4);
    float* h2   = (float*)alloc((size_t)NN2 * DH * 4);
    float* agg2 = (float*)alloc((size_t)NN3 * DH * 4);
    float* z    = (float*)alloc((size_t)NN3 * DOUT * 4);

    int* cnt0  = (int*)alloc((size_t)NN1 * 4);
    int* rp0   = (int*)alloc((size_t)(NN1 + 1) * 4);
    int* cur0  = (int*)alloc((size_t)NN1 * 4);
    int* eidx0 = (int*)alloc((size_t)EE0 * 4);
    int* cnt1  = (int*)alloc((size_t)NN2 * 4);
    int* rp1   = (int*)alloc((size_t)(NN2 + 1) * 4);
    int* cur1  = (int*)alloc((size_t)NN2 * 4);
    int* eidx1 = (int*)alloc((size_t)EE1 * 4);
    int* cnt2  = (int*)alloc((size_t)NN3 * 4);
    int* rp2   = (int*)alloc((size_t)(NN3 + 1) * 4);
    int* cur2  = (int*)alloc((size_t)NN3 * 4);
    int* eidx2 = (int*)alloc((size_t)EE2 * 4);
    int* part  = (int*)alloc(256 * 4);

    // ---- layer 0 ----
    build_csr(e0s, e0d, EE0, NN1, cnt0, part, rp0, cur0, eidx0, stream);
    agg_mean_100<<<NN1, 128, 0, stream>>>(x, rp0, eidx0, agg0);
    {
        dim3 grid((DH + 63) / 64, (NN1 + 63) / 64);
        dual_gemm<1><<<grid, 256, 0, stream>>>(agg0, x, Wl0, Wr0, b0, h1,
                                               NN1, DH, DIN);
    }

    // ---- layer 1 ----
    build_csr(e1s, e1d, EE1, NN2, cnt1, part, rp1, cur1, eidx1, stream);
    agg_mean_256<<<NN2, 256, 0, stream>>>(h1, rp1, eidx1, agg1);
    {
        dim3 grid((DH + 63) / 64, (NN2 + 63) / 64);
        dual_gemm<1><<<grid, 256, 0, stream>>>(agg1, h1, Wl1, Wr1, b1, h2,
                                               NN2, DH, DH);
    }

    // ---- layer 2 ----
    build_csr(e2s, e2d, EE2, NN3, cnt2, part, rp2, cur2, eidx2, stream);
    agg_mean_256<<<NN3, 256, 0, stream>>>(h2, rp2, eidx2, agg2);
    {
        dim3 grid((DOUT + 63) / 64, (NN3 + 63) / 64);
        dual_gemm<0><<<grid, 256, 0, stream>>>(agg2, h2, Wl2, Wr2, b2, z,
                                               NN3, DOUT, DH);
    }

    // ---- log_softmax ----
    log_softmax_47<<<NN3, 64, 0, stream>>>(z, (float*)d_out);
}

// Round 3
// 655.061 us; speedup vs baseline: 6.3599x; 2.1544x over previous
//
#include <hip/hip_runtime.h>

#define NN0 600000
#define NN1 100000
#define NN2 20000
#define NN3 4096
#define EE0 1500000
#define EE1 200000
#define EE2 40960
#define DIN 100
#define DH  256
#define DOUT 47

typedef unsigned int uint;
typedef unsigned short ushort;
typedef __attribute__((ext_vector_type(8))) short bhalf8;
typedef __attribute__((ext_vector_type(4))) float f32x4;

union U16B {
    uint2  u2[2];
    uint4  u4;
    bhalf8 s8;
    ushort us[8];
};

__device__ __forceinline__ ushort f2bf(float f) {
    uint u = __float_as_uint(f);
    uint r = (u + 0x7FFFu + ((u >> 16) & 1u)) >> 16;
    return (ushort)r;
}
__device__ __forceinline__ float bf2f(uint bits16) {
    return __uint_as_float(bits16 << 16);
}

// ================= CSR build =================================================

__global__ void hist_kernel(const int* __restrict__ dst, int E, int* __restrict__ cnt) {
    for (int e = blockIdx.x * blockDim.x + threadIdx.x; e < E;
         e += gridDim.x * blockDim.x)
        atomicAdd(&cnt[dst[e]], 1);
}

__global__ void scan1(const int* __restrict__ cnt, int n, int* __restrict__ part) {
    __shared__ int s[256];
    int base = blockIdx.x * 1024;
    int sum = 0;
    for (int i = threadIdx.x; i < 1024; i += 256) {
        int idx = base + i;
        sum += (idx < n) ? cnt[idx] : 0;
    }
    s[threadIdx.x] = sum;
    __syncthreads();
    for (int off = 128; off; off >>= 1) {
        if (threadIdx.x < off) s[threadIdx.x] += s[threadIdx.x + off];
        __syncthreads();
    }
    if (threadIdx.x == 0) part[blockIdx.x] = s[0];
}

__global__ void scan2(int* part, int nb) {
    if (threadIdx.x == 0 && blockIdx.x == 0) {
        int run = 0;
        for (int i = 0; i < nb; ++i) { int v = part[i]; part[i] = run; run += v; }
    }
}

__global__ void scan3(const int* __restrict__ cnt, int n, const int* __restrict__ part,
                      int* __restrict__ row_ptr, int* __restrict__ cursor) {
    __shared__ int s[256];
    int base = blockIdx.x * 1024;
    int v[4];
    int sum = 0;
    #pragma unroll
    for (int j = 0; j < 4; ++j) {
        int idx = base + threadIdx.x * 4 + j;
        v[j] = (idx < n) ? cnt[idx] : 0;
        sum += v[j];
    }
    s[threadIdx.x] = sum;
    __syncthreads();
    for (int off = 1; off < 256; off <<= 1) {
        int t = (threadIdx.x >= off) ? s[threadIdx.x - off] : 0;
        __syncthreads();
        s[threadIdx.x] += t;
        __syncthreads();
    }
    int off0 = part[blockIdx.x] + s[threadIdx.x] - sum;
    #pragma unroll
    for (int j = 0; j < 4; ++j) {
        int idx = base + threadIdx.x * 4 + j;
        if (idx < n) {
            row_ptr[idx] = off0;
            cursor[idx]  = off0;
            off0 += v[j];
            if (idx == n - 1) row_ptr[n] = off0;
        }
    }
}

__global__ void build_eidx(const int* __restrict__ src, const int* __restrict__ dst,
                           int E, int* __restrict__ cursor, int* __restrict__ eidx) {
    for (int e = blockIdx.x * blockDim.x + threadIdx.x; e < E;
         e += gridDim.x * blockDim.x) {
        int pos = atomicAdd(&cursor[dst[e]], 1);
        eidx[pos] = src[e];
    }
}

// ================= conversions ==============================================

// elementwise f32 -> bf16, n must be multiple of 4
__global__ void conv_bf16(const float* __restrict__ in, ushort* __restrict__ out,
                          long long n4) {
    long long t = (long long)blockIdx.x * blockDim.x + threadIdx.x;
    if (t >= n4) return;
    float4 v = *reinterpret_cast<const float4*>(in + t * 4);
    uint lo = (uint)f2bf(v.x) | ((uint)f2bf(v.y) << 16);
    uint hi = (uint)f2bf(v.z) | ((uint)f2bf(v.w) << 16);
    uint2 o; o.x = lo; o.y = hi;
    *reinterpret_cast<uint2*>(out + t * 4) = o;
}

// pack weight B [K x N] f32 row-major into MFMA B-fragment layout:
// out[((kstep*NB + cblock)*64 + lane)*8 + j] = B[kstep*32 + (lane>>4)*8 + j][cblock*16 + (lane&15)]
__global__ void pack_B(const float* __restrict__ B, int K, int N, int NB,
                       ushort* __restrict__ out) {
    int l = threadIdx.x;              // 0..63
    int kstep = blockIdx.x / NB;
    int c = blockIdx.x % NB;
    U16B v;
    #pragma unroll
    for (int j = 0; j < 8; ++j) {
        int k = kstep * 32 + ((l >> 4) << 3) + j;
        int col = (c << 4) | (l & 15);
        float f = (k < K && col < N) ? B[(size_t)k * N + col] : 0.0f;
        v.us[j] = f2bf(f);
    }
    *reinterpret_cast<bhalf8*>(out + ((size_t)blockIdx.x * 64 + l) * 8) = v.s8;
}

// ================= pull aggregation (fp32 accum, bf16 out, mean folded) ======

// D=100, gather from fp32 x. wave per node, lane l covers cols 2l,2l+1 (l<50).
__global__ __launch_bounds__(256)
void agg100_f(const float* __restrict__ x, const int* __restrict__ rp,
              const int* __restrict__ eidx, ushort* __restrict__ out, int nNodes) {
    int node = blockIdx.x * 4 + (threadIdx.x >> 6);
    if (node >= nNodes) return;
    int l = threadIdx.x & 63;
    bool act = l < 50;
    int beg = rp[node], end = rp[node + 1];
    float a0 = 0.f, a1 = 0.f;
    int j = beg;
    for (; j + 1 < end; j += 2) {
        int s0 = eidx[j], s1 = eidx[j + 1];
        if (act) {
            float2 v0 = *reinterpret_cast<const float2*>(x + (size_t)s0 * DIN + l * 2);
            float2 v1 = *reinterpret_cast<const float2*>(x + (size_t)s1 * DIN + l * 2);
            a0 += v0.x + v1.x;
            a1 += v0.y + v1.y;
        }
    }
    if (j < end) {
        int s0 = eidx[j];
        if (act) {
            float2 v0 = *reinterpret_cast<const float2*>(x + (size_t)s0 * DIN + l * 2);
            a0 += v0.x; a1 += v0.y;
        }
    }
    float inv = 1.0f / fmaxf((float)(end - beg), 1.0f);
    if (act) {
        uint o = (uint)f2bf(a0 * inv) | ((uint)f2bf(a1 * inv) << 16);
        *reinterpret_cast<uint*>(out + (size_t)node * DIN + l * 2) = o;
    }
}

// D=100, gather from bf16 x.
__global__ __launch_bounds__(256)
void agg100_b(const ushort* __restrict__ xb, const int* __restrict__ rp,
              const int* __restrict__ eidx, ushort* __restrict__ out, int nNodes) {
    int node = blockIdx.x * 4 + (threadIdx.x >> 6);
    if (node >= nNodes) return;
    int l = threadIdx.x & 63;
    bool act = l < 50;
    int beg = rp[node], end = rp[node + 1];
    float a0 = 0.f, a1 = 0.f;
    int j = beg;
    for (; j + 1 < end; j += 2) {
        int s0 = eidx[j], s1 = eidx[j + 1];
        if (act) {
            uint v0 = *reinterpret_cast<const uint*>(xb + (size_t)s0 * DIN + l * 2);
            uint v1 = *reinterpret_cast<const uint*>(xb + (size_t)s1 * DIN + l * 2);
            a0 += bf2f(v0 & 0xffffu) + bf2f(v1 & 0xffffu);
            a1 += bf2f(v0 >> 16) + bf2f(v1 >> 16);
        }
    }
    if (j < end) {
        int s0 = eidx[j];
        if (act) {
            uint v0 = *reinterpret_cast<const uint*>(xb + (size_t)s0 * DIN + l * 2);
            a0 += bf2f(v0 & 0xffffu);
            a1 += bf2f(v0 >> 16);
        }
    }
    float inv = 1.0f / fmaxf((float)(end - beg), 1.0f);
    if (act) {
        uint o = (uint)f2bf(a0 * inv) | ((uint)f2bf(a1 * inv) << 16);
        *reinterpret_cast<uint*>(out + (size_t)node * DIN + l * 2) = o;
    }
}

// D=256, gather from bf16 h. lane l covers cols 4l..4l+3.
__global__ __launch_bounds__(256)
void agg256_b(const ushort* __restrict__ h, const int* __restrict__ rp,
              const int* __restrict__ eidx, ushort* __restrict__ out, int nNodes) {
    int node = blockIdx.x * 4 + (threadIdx.x >> 6);
    if (node >= nNodes) return;
    int l = threadIdx.x & 63;
    int beg = rp[node], end = rp[node + 1];
    float a0 = 0.f, a1 = 0.f, a2 = 0.f, a3 = 0.f;
    int j = beg;
    for (; j + 1 < end; j += 2) {
        int s0 = eidx[j], s1 = eidx[j + 1];
        uint2 v0 = *reinterpret_cast<const uint2*>(h + (size_t)s0 * DH + l * 4);
        uint2 v1 = *reinterpret_cast<const uint2*>(h + (size_t)s1 * DH + l * 4);
        a0 += bf2f(v0.x & 0xffffu) + bf2f(v1.x & 0xffffu);
        a1 += bf2f(v0.x >> 16)     + bf2f(v1.x >> 16);
        a2 += bf2f(v0.y & 0xffffu) + bf2f(v1.y & 0xffffu);
        a3 += bf2f(v0.y >> 16)     + bf2f(v1.y >> 16);
    }
    if (j < end) {
        int s0 = eidx[j];
        uint2 v0 = *reinterpret_cast<const uint2*>(h + (size_t)s0 * DH + l * 4);
        a0 += bf2f(v0.x & 0xffffu);
        a1 += bf2f(v0.x >> 16);
        a2 += bf2f(v0.y & 0xffffu);
        a3 += bf2f(v0.y >> 16);
    }
    float inv = 1.0f / fmaxf((float)(end - beg), 1.0f);
    uint2 o;
    o.x = (uint)f2bf(a0 * inv) | ((uint)f2bf(a1 * inv) << 16);
    o.y = (uint)f2bf(a2 * inv) | ((uint)f2bf(a3 * inv) << 16);
    *reinterpret_cast<uint2*>(out + (size_t)node * DH + l * 4) = o;
}

// ================= dual MFMA GEMM ===========================================
// C[M,N] = A1[M,K1] @ B1[K1,N] + A2[M,K2] @ B2[K2,N] + bias ; optional ReLU.
// A row-major bf16 (str in elems), B pre-packed fragment layout, 64-row tile,
// 256 threads (4 waves), wave w owns col fragments c = w*NBW + i (i<NBW).
template <int RELU, int OUTBF>
__global__ __launch_bounds__(256)
void gemm_dual(const ushort* __restrict__ A1, int K1, int S1, int str1,
               const ushort* __restrict__ A2, int K2, int S2, int str2,
               const ushort* __restrict__ B1p, const ushort* __restrict__ B2p,
               const float* __restrict__ bias, void* __restrict__ Cv,
               int M, int N, int NB, int NBW, int Cstride) {
    __shared__ ushort At[2][2048];   // 64 rows x 32 k, fragment-ordered, dbuf

    const int tid = threadIdx.x;
    const int w = tid >> 6;
    const int l = tid & 63;
    const int m0 = blockIdx.x * 64;
    const int S = S1 + S2;

    f32x4 acc[4][4];
    #pragma unroll
    for (int m = 0; m < 4; ++m)
        #pragma unroll
        for (int i = 0; i < 4; ++i)
            acc[m][i] = f32x4{0.f, 0.f, 0.f, 0.f};

    auto stage = [&](int s, int buf) {
        const ushort* A; int str, Keff, ks;
        if (s < S1) { A = A1; str = str1; Keff = K1; ks = s; }
        else        { A = A2; str = str2; Keff = K2; ks = s - S1; }
        int r  = tid >> 2;       // 0..63 row within tile
        int kc = tid & 3;        // k-group
        int row = m0 + r;
        int k = ks * 32 + (kc << 3);
        U16B v;
        v.u4.x = v.u4.y = v.u4.z = v.u4.w = 0u;
        if (row < M && k < Keff) {
            const ushort* p = A + (size_t)row * str + k;
            v.u2[0] = *reinterpret_cast<const uint2*>(p);
            v.u2[1] = *reinterpret_cast<const uint2*>(p + 4);
            if (k + 8 > Keff) {
                #pragma unroll
                for (int j = 0; j < 8; ++j)
                    if (k + j >= Keff) v.us[j] = 0;
            }
        }
        int slot = ((r >> 4) << 6) | (r & 15) | (kc << 4);
        *reinterpret_cast<bhalf8*>(&At[buf][slot * 8]) = v.s8;
    };

    stage(0, 0);
    __syncthreads();

    for (int s = 0; s < S; ++s) {
        int buf = s & 1;
        if (s + 1 < S) stage(s + 1, buf ^ 1);

        const ushort* Bp; int ks;
        if (s < S1) { Bp = B1p; ks = s; }
        else        { Bp = B2p; ks = s - S1; }

        bhalf8 a[4];
        #pragma unroll
        for (int m = 0; m < 4; ++m)
            a[m] = *reinterpret_cast<bhalf8*>(&At[buf][((m << 6) | l) * 8]);

        #pragma unroll
        for (int i = 0; i < 4; ++i) {
            if (i < NBW) {
                int c = w * NBW + i;
                if (c < NB) {
                    bhalf8 b = *reinterpret_cast<const bhalf8*>(
                        Bp + ((size_t)(ks * NB + c) * 64 + l) * 8);
                    #pragma unroll
                    for (int m = 0; m < 4; ++m)
                        acc[m][i] = __builtin_amdgcn_mfma_f32_16x16x32_bf16(
                            a[m], b, acc[m][i], 0, 0, 0);
                }
            }
        }
        __syncthreads();
    }

    // epilogue: D mapping col = lane&15, row = (lane>>4)*4 + reg
    #pragma unroll
    for (int i = 0; i < 4; ++i) {
        if (i >= NBW) continue;
        int c = w * NBW + i;
        if (c >= NB) continue;
        int col = (c << 4) | (l & 15);
        if (col >= N) continue;
        float bb = bias[col];
        #pragma unroll
        for (int m = 0; m < 4; ++m) {
            #pragma unroll
            for (int e = 0; e < 4; ++e) {
                int row = m0 + (m << 4) + ((l >> 4) << 2) + e;
                if (row < M) {
                    float v = acc[m][i][e] + bb;
                    if (RELU) v = fmaxf(v, 0.0f);
                    if (OUTBF)
                        ((ushort*)Cv)[(size_t)row * Cstride + col] = f2bf(v);
                    else
                        ((float*)Cv)[(size_t)row * Cstride + col] = v;
                }
            }
        }
    }
}

// ================= log_softmax over 47 classes ==============================
__global__ void log_softmax_47(const float* __restrict__ z, float* __restrict__ out) {
    int row = blockIdx.x;
    int lane = threadIdx.x;
    float v = (lane < DOUT) ? z[(size_t)row * DOUT + lane] : -INFINITY;
    float m = v;
    #pragma unroll
    for (int off = 32; off; off >>= 1) m = fmaxf(m, __shfl_xor(m, off));
    float e = (lane < DOUT) ? expf(v - m) : 0.0f;
    float s = e;
    #pragma unroll
    for (int off = 32; off; off >>= 1) s += __shfl_xor(s, off);
    if (lane < DOUT) out[(size_t)row * DOUT + lane] = v - m - logf(s);
}

// ================= launch ====================================================
static void build_csr(const int* src, const int* dst, int E, int n,
                      int* cnt, int* part, int* row_ptr, int* cursor, int* eidx,
                      hipStream_t stream) {
    hipMemsetAsync(cnt, 0, (size_t)n * 4, stream);
    hist_kernel<<<1024, 256, 0, stream>>>(dst, E, cnt);
    int nb = (n + 1023) / 1024;
    scan1<<<nb, 256, 0, stream>>>(cnt, n, part);
    scan2<<<1, 64, 0, stream>>>(part, nb);
    scan3<<<nb, 256, 0, stream>>>(cnt, n, part, row_ptr, cursor);
    build_eidx<<<1024, 256, 0, stream>>>(src, dst, E, cursor, eidx);
}

extern "C" void kernel_launch(void* const* d_in, const int* in_sizes, int n_in,
                              void* d_out, int out_size, void* d_ws, size_t ws_size,
                              hipStream_t stream) {
    const float* x   = (const float*)d_in[0];
    const int* e0s   = (const int*)d_in[1];
    const int* e0d   = (const int*)d_in[2];
    const int* e1s   = (const int*)d_in[3];
    const int* e1d   = (const int*)d_in[4];
    const int* e2s   = (const int*)d_in[5];
    const int* e2d   = (const int*)d_in[6];
    const float* Wl0 = (const float*)d_in[7];
    const float* Wr0 = (const float*)d_in[8];
    const float* b0  = (const float*)d_in[9];
    const float* Wl1 = (const float*)d_in[10];
    const float* Wr1 = (const float*)d_in[11];
    const float* b1  = (const float*)d_in[12];
    const float* Wl2 = (const float*)d_in[13];
    const float* Wr2 = (const float*)d_in[14];
    const float* b2  = (const float*)d_in[15];

    char* ws = (char*)d_ws;
    size_t off = 0;
    auto alloc = [&](size_t bytes) -> void* {
        void* p = ws + off;
        off += (bytes + 255) & ~(size_t)255;
        return p;
    };

    ushort* agg0b = (ushort*)alloc((size_t)NN1 * DIN * 2);
    ushort* h1    = (ushort*)alloc((size_t)NN1 * DH * 2);
    ushort* agg1b = (ushort*)alloc((size_t)NN2 * DH * 2);
    ushort* h2    = (ushort*)alloc((size_t)NN2 * DH * 2);
    ushort* agg2b = (ushort*)alloc((size_t)NN3 * DH * 2);
    float*  z     = (float*)alloc((size_t)NN3 * DOUT * 4);

    // packed weights: [Ksteps][NB][64 lanes][8] bf16
    ushort* Bp0l = (ushort*)alloc((size_t)4 * 16 * 64 * 8 * 2);
    ushort* Bp0r = (ushort*)alloc((size_t)4 * 16 * 64 * 8 * 2);
    ushort* Bp1l = (ushort*)alloc((size_t)8 * 16 * 64 * 8 * 2);
    ushort* Bp1r = (ushort*)alloc((size_t)8 * 16 * 64 * 8 * 2);
    ushort* Bp2l = (ushort*)alloc((size_t)8 * 3 * 64 * 8 * 2);
    ushort* Bp2r = (ushort*)alloc((size_t)8 * 3 * 64 * 8 * 2);

    int* cnt0  = (int*)alloc((size_t)NN1 * 4);
    int* rp0   = (int*)alloc((size_t)(NN1 + 1) * 4);
    int* cur0  = (int*)alloc((size_t)NN1 * 4);
    int* eidx0 = (int*)alloc((size_t)EE0 * 4);
    int* cnt1  = (int*)alloc((size_t)NN2 * 4);
    int* rp1   = (int*)alloc((size_t)(NN2 + 1) * 4);
    int* cur1  = (int*)alloc((size_t)NN2 * 4);
    int* eidx1 = (int*)alloc((size_t)EE1 * 4);
    int* cnt2  = (int*)alloc((size_t)NN3 * 4);
    int* rp2   = (int*)alloc((size_t)(NN3 + 1) * 4);
    int* cur2  = (int*)alloc((size_t)NN3 * 4);
    int* eidx2 = (int*)alloc((size_t)EE2 * 4);
    int* part  = (int*)alloc(256 * 4);

    // x in bf16: full table if workspace allows (halves agg0 gather bytes),
    // else only the first NN1 rows (needed as the dense GEMM operand).
    size_t fullNeed = (size_t)NN0 * DIN * 2 + 4096;
    bool big = (ws_size - off) >= fullNeed;
    int xRows = big ? NN0 : NN1;
    ushort* xb = (ushort*)alloc((size_t)xRows * DIN * 2 + 256);

    // ---- weight packing (tiny, independent) ----
    pack_B<<<4 * 16, 64, 0, stream>>>(Wl0, DIN, DH, 16, Bp0l);
    pack_B<<<4 * 16, 64, 0, stream>>>(Wr0, DIN, DH, 16, Bp0r);
    pack_B<<<8 * 16, 64, 0, stream>>>(Wl1, DH, DH, 16, Bp1l);
    pack_B<<<8 * 16, 64, 0, stream>>>(Wr1, DH, DH, 16, Bp1r);
    pack_B<<<8 * 3, 64, 0, stream>>>(Wl2, DH, DOUT, 3, Bp2l);
    pack_B<<<8 * 3, 64, 0, stream>>>(Wr2, DH, DOUT, 3, Bp2r);

    // ---- x -> bf16 ----
    {
        long long n4 = (long long)xRows * DIN / 4;
        conv_bf16<<<(unsigned)((n4 + 255) / 256), 256, 0, stream>>>(x, xb, n4);
    }

    // ---- layer 0 ----
    build_csr(e0s, e0d, EE0, NN1, cnt0, part, rp0, cur0, eidx0, stream);
    if (big)
        agg100_b<<<(NN1 + 3) / 4, 256, 0, stream>>>(xb, rp0, eidx0, agg0b, NN1);
    else
        agg100_f<<<(NN1 + 3) / 4, 256, 0, stream>>>(x, rp0, eidx0, agg0b, NN1);
    gemm_dual<1, 1><<<(NN1 + 63) / 64, 256, 0, stream>>>(
        agg0b, DIN, 4, DIN, xb, DIN, 4, DIN, Bp0l, Bp0r, b0, h1,
        NN1, DH, 16, 4, DH);

    // ---- layer 1 ----
    build_csr(e1s, e1d, EE1, NN2, cnt1, part, rp1, cur1, eidx1, stream);
    agg256_b<<<(NN2 + 3) / 4, 256, 0, stream>>>(h1, rp1, eidx1, agg1b, NN2);
    gemm_dual<1, 1><<<(NN2 + 63) / 64, 256, 0, stream>>>(
        agg1b, DH, 8, DH, h1, DH, 8, DH, Bp1l, Bp1r, b1, h2,
        NN2, DH, 16, 4, DH);

    // ---- layer 2 ----
    build_csr(e2s, e2d, EE2, NN3, cnt2, part, rp2, cur2, eidx2, stream);
    agg256_b<<<(NN3 + 3) / 4, 256, 0, stream>>>(h2, rp2, eidx2, agg2b, NN3);
    gemm_dual<0, 0><<<(NN3 + 63) / 64, 256, 0, stream>>>(
        agg2b, DH, 8, DH, h2, DH, 8, DH, Bp2l, Bp2r, b2, z,
        NN3, DOUT, 3, 1, DOUT);

    // ---- log_softmax ----
    log_softmax_47<<<NN3, 64, 0, stream>>>(z, (float*)d_out);
}

// Round 4
// 550.291 us; speedup vs baseline: 7.5708x; 1.1904x over previous
//
#include <hip/hip_runtime.h>

#define NN0 600000
#define NN1 100000
#define NN2 20000
#define NN3 4096
#define EE0 1500000
#define EE1 200000
#define EE2 40960
#define DIN 100
#define DH  256
#define DOUT 47

// fused scan geometry: ceil(N/1024) blocks per layer
#define NB0 98
#define NB1 20
#define NB2 4
#define NBT 122   // NB0+NB1+NB2

typedef unsigned int uint;
typedef unsigned short ushort;
typedef __attribute__((ext_vector_type(8))) short bhalf8;
typedef __attribute__((ext_vector_type(4))) float f32x4;

union U16B {
    uint2  u2[2];
    uint4  u4;
    bhalf8 s8;
    ushort us[8];
};

__device__ __forceinline__ ushort f2bf(float f) {
    uint u = __float_as_uint(f);
    uint r = (u + 0x7FFFu + ((u >> 16) & 1u)) >> 16;
    return (ushort)r;
}
__device__ __forceinline__ float bf2f(uint bits16) {
    return __uint_as_float(bits16 << 16);
}

// ================= mega kernel 1: x->bf16 conversion + 3 histograms ==========
// blocks [0,3072): conv; [3072,3840): hist L0; [3840,3968): hist L1; rest: hist L2
__global__ __launch_bounds__(256)
void mega1(const float* __restrict__ x, ushort* __restrict__ xb, long long n4,
           const int* __restrict__ e0d, const int* __restrict__ e1d,
           const int* __restrict__ e2d, int* __restrict__ cntAll) {
    int b = blockIdx.x;
    if (b < 3072) {
        for (long long t = (long long)b * 256 + threadIdx.x; t < n4;
             t += 3072LL * 256) {
            float4 v = *reinterpret_cast<const float4*>(x + t * 4);
            uint2 o;
            o.x = (uint)f2bf(v.x) | ((uint)f2bf(v.y) << 16);
            o.y = (uint)f2bf(v.z) | ((uint)f2bf(v.w) << 16);
            *reinterpret_cast<uint2*>(xb + t * 4) = o;
        }
    } else if (b < 3840) {
        int bb = b - 3072;
        for (int e = bb * 256 + threadIdx.x; e < EE0; e += 768 * 256)
            atomicAdd(&cntAll[e0d[e]], 1);
    } else if (b < 3968) {
        int bb = b - 3840;
        for (int e = bb * 256 + threadIdx.x; e < EE1; e += 128 * 256)
            atomicAdd(&cntAll[NN1 + e1d[e]], 1);
    } else {
        int bb = b - 3968;
        for (int e = bb * 256 + threadIdx.x; e < EE2; e += 32 * 256)
            atomicAdd(&cntAll[NN1 + NN2 + e2d[e]], 1);
    }
}

// ================= fused CSR scans ==========================================

__device__ __forceinline__ void layer_of(int b, int& lb, int& n, int& po, int& cb) {
    if (b < NB0)      { lb = b;        n = NN1; po = 0;         cb = 0; }
    else if (b < NB0 + NB1) { lb = b - NB0;  n = NN2; po = NB0; cb = NN1; }
    else              { lb = b - NB0 - NB1; n = NN3; po = NB0 + NB1; cb = NN1 + NN2; }
}

__global__ void scan1f(const int* __restrict__ cntAll, int* __restrict__ part) {
    int lb, n, po, cb;
    layer_of(blockIdx.x, lb, n, po, cb);
    __shared__ int s[256];
    int base = lb * 1024;
    int sum = 0;
    for (int i = threadIdx.x; i < 1024; i += 256) {
        int idx = base + i;
        sum += (idx < n) ? cntAll[cb + idx] : 0;
    }
    s[threadIdx.x] = sum;
    __syncthreads();
    for (int off = 128; off; off >>= 1) {
        if (threadIdx.x < off) s[threadIdx.x] += s[threadIdx.x + off];
        __syncthreads();
    }
    if (threadIdx.x == 0) part[po + lb] = s[0];
}

// segmented exclusive scan over the 122 partials, one block of 128 threads
__global__ void scan2f(int* part) {
    __shared__ int s[128];
    int t = threadIdx.x;
    int seg = (t < NB0) ? 0 : (t < NB0 + NB1) ? 1 : (t < NBT) ? 2 : 3;
    int v = (t < NBT) ? part[t] : 0;
    s[t] = v;
    __syncthreads();
    for (int off = 1; off < 128; off <<= 1) {
        int add = 0;
        if (t >= off) {
            int u = t - off;
            int segu = (u < NB0) ? 0 : (u < NB0 + NB1) ? 1 : (u < NBT) ? 2 : 3;
            if (segu == seg) add = s[u];
        }
        __syncthreads();
        s[t] += add;
        __syncthreads();
    }
    if (t < NBT) part[t] = s[t] - v;   // exclusive within segment
}

__global__ void scan3f(const int* __restrict__ cntAll, const int* __restrict__ part,
                       int* __restrict__ rp0, int* __restrict__ cur0,
                       int* __restrict__ rp1, int* __restrict__ cur1,
                       int* __restrict__ rp2, int* __restrict__ cur2) {
    int lb, n, po, cb;
    layer_of(blockIdx.x, lb, n, po, cb);
    int* row_ptr; int* cursor;
    if (cb == 0)        { row_ptr = rp0; cursor = cur0; }
    else if (cb == NN1) { row_ptr = rp1; cursor = cur1; }
    else                { row_ptr = rp2; cursor = cur2; }

    __shared__ int s[256];
    int base = lb * 1024;
    int v[4];
    int sum = 0;
    #pragma unroll
    for (int j = 0; j < 4; ++j) {
        int idx = base + threadIdx.x * 4 + j;
        v[j] = (idx < n) ? cntAll[cb + idx] : 0;
        sum += v[j];
    }
    s[threadIdx.x] = sum;
    __syncthreads();
    for (int off = 1; off < 256; off <<= 1) {
        int t = (threadIdx.x >= off) ? s[threadIdx.x - off] : 0;
        __syncthreads();
        s[threadIdx.x] += t;
        __syncthreads();
    }
    int off0 = part[po + lb] + s[threadIdx.x] - sum;
    #pragma unroll
    for (int j = 0; j < 4; ++j) {
        int idx = base + threadIdx.x * 4 + j;
        if (idx < n) {
            row_ptr[idx] = off0;
            cursor[idx]  = off0;
            off0 += v[j];
            if (idx == n - 1) row_ptr[n] = off0;
        }
    }
}

// fused eidx build: [0,768) L0, [768,896) L1, [896,928) L2
__global__ __launch_bounds__(256)
void build_eidxf(const int* __restrict__ e0s, const int* __restrict__ e0d,
                 const int* __restrict__ e1s, const int* __restrict__ e1d,
                 const int* __restrict__ e2s, const int* __restrict__ e2d,
                 int* __restrict__ cur0, int* __restrict__ cur1, int* __restrict__ cur2,
                 int* __restrict__ eidx0, int* __restrict__ eidx1, int* __restrict__ eidx2) {
    int b = blockIdx.x;
    const int* src; const int* dst; int* cursor; int* eidx; int E, bb, nb;
    if (b < 768)      { src = e0s; dst = e0d; cursor = cur0; eidx = eidx0; E = EE0; bb = b; nb = 768; }
    else if (b < 896) { src = e1s; dst = e1d; cursor = cur1; eidx = eidx1; E = EE1; bb = b - 768; nb = 128; }
    else              { src = e2s; dst = e2d; cursor = cur2; eidx = eidx2; E = EE2; bb = b - 896; nb = 32; }
    for (int e = bb * 256 + threadIdx.x; e < E; e += nb * 256) {
        int pos = atomicAdd(&cursor[dst[e]], 1);
        eidx[pos] = src[e];
    }
}

// ================= fused weight pack ========================================
// out[((kstep*NB + cblock)*64 + lane)*8 + j] = B[kstep*32 + (lane>>4)*8 + j][cblock*16 + (lane&15)]
__device__ __forceinline__ void pack_one(const float* B, int K, int N, int NB,
                                         ushort* out, int bid, int l) {
    int kstep = bid / NB;
    int c = bid % NB;
    U16B v;
    #pragma unroll
    for (int j = 0; j < 8; ++j) {
        int k = kstep * 32 + ((l >> 4) << 3) + j;
        int col = (c << 4) | (l & 15);
        float f = (k < K && col < N) ? B[(size_t)k * N + col] : 0.0f;
        v.us[j] = f2bf(f);
    }
    *reinterpret_cast<bhalf8*>(out + ((size_t)bid * 64 + l) * 8) = v.s8;
}

__global__ void pack_all(const float* __restrict__ Wl0, const float* __restrict__ Wr0,
                         const float* __restrict__ Wl1, const float* __restrict__ Wr1,
                         const float* __restrict__ Wl2, const float* __restrict__ Wr2,
                         ushort* Bp0l, ushort* Bp0r, ushort* Bp1l, ushort* Bp1r,
                         ushort* Bp2l, ushort* Bp2r) {
    int b = blockIdx.x, l = threadIdx.x;
    if (b < 64)        pack_one(Wl0, DIN, DH,   16, Bp0l, b,       l);
    else if (b < 128)  pack_one(Wr0, DIN, DH,   16, Bp0r, b - 128 + 64, l);
    else if (b < 256)  pack_one(Wl1, DH,  DH,   16, Bp1l, b - 128, l);
    else if (b < 384)  pack_one(Wr1, DH,  DH,   16, Bp1r, b - 256, l);
    else if (b < 408)  pack_one(Wl2, DH,  DOUT,  3, Bp2l, b - 384, l);
    else               pack_one(Wr2, DH,  DOUT,  3, Bp2r, b - 408, l);
}

// ================= pull aggregation (fp32 accum, bf16 out, mean folded) ======

// D=100, gather from bf16 x; 4x neighbor unroll.
__global__ __launch_bounds__(256)
void agg100_b(const ushort* __restrict__ xb, const int* __restrict__ rp,
              const int* __restrict__ eidx, ushort* __restrict__ out, int nNodes) {
    int node = blockIdx.x * 4 + (threadIdx.x >> 6);
    if (node >= nNodes) return;
    int l = threadIdx.x & 63;
    bool act = l < 50;
    int beg = rp[node], end = rp[node + 1];
    float a0 = 0.f, a1 = 0.f;
    int j = beg;
    for (; j + 3 < end; j += 4) {
        int s0 = eidx[j], s1 = eidx[j + 1], s2 = eidx[j + 2], s3 = eidx[j + 3];
        if (act) {
            uint v0 = *reinterpret_cast<const uint*>(xb + (size_t)s0 * DIN + l * 2);
            uint v1 = *reinterpret_cast<const uint*>(xb + (size_t)s1 * DIN + l * 2);
            uint v2 = *reinterpret_cast<const uint*>(xb + (size_t)s2 * DIN + l * 2);
            uint v3 = *reinterpret_cast<const uint*>(xb + (size_t)s3 * DIN + l * 2);
            a0 += bf2f(v0 & 0xffffu) + bf2f(v1 & 0xffffu) + bf2f(v2 & 0xffffu) + bf2f(v3 & 0xffffu);
            a1 += bf2f(v0 >> 16) + bf2f(v1 >> 16) + bf2f(v2 >> 16) + bf2f(v3 >> 16);
        }
    }
    for (; j < end; ++j) {
        int s0 = eidx[j];
        if (act) {
            uint v0 = *reinterpret_cast<const uint*>(xb + (size_t)s0 * DIN + l * 2);
            a0 += bf2f(v0 & 0xffffu);
            a1 += bf2f(v0 >> 16);
        }
    }
    float inv = 1.0f / fmaxf((float)(end - beg), 1.0f);
    if (act) {
        uint o = (uint)f2bf(a0 * inv) | ((uint)f2bf(a1 * inv) << 16);
        *reinterpret_cast<uint*>(out + (size_t)node * DIN + l * 2) = o;
    }
}

// D=100, gather from fp32 x (fallback when xb table doesn't fit).
__global__ __launch_bounds__(256)
void agg100_f(const float* __restrict__ x, const int* __restrict__ rp,
              const int* __restrict__ eidx, ushort* __restrict__ out, int nNodes) {
    int node = blockIdx.x * 4 + (threadIdx.x >> 6);
    if (node >= nNodes) return;
    int l = threadIdx.x & 63;
    bool act = l < 50;
    int beg = rp[node], end = rp[node + 1];
    float a0 = 0.f, a1 = 0.f;
    int j = beg;
    for (; j + 1 < end; j += 2) {
        int s0 = eidx[j], s1 = eidx[j + 1];
        if (act) {
            float2 v0 = *reinterpret_cast<const float2*>(x + (size_t)s0 * DIN + l * 2);
            float2 v1 = *reinterpret_cast<const float2*>(x + (size_t)s1 * DIN + l * 2);
            a0 += v0.x + v1.x;
            a1 += v0.y + v1.y;
        }
    }
    if (j < end) {
        int s0 = eidx[j];
        if (act) {
            float2 v0 = *reinterpret_cast<const float2*>(x + (size_t)s0 * DIN + l * 2);
            a0 += v0.x; a1 += v0.y;
        }
    }
    float inv = 1.0f / fmaxf((float)(end - beg), 1.0f);
    if (act) {
        uint o = (uint)f2bf(a0 * inv) | ((uint)f2bf(a1 * inv) << 16);
        *reinterpret_cast<uint*>(out + (size_t)node * DIN + l * 2) = o;
    }
}

// D=256, gather from bf16 h. lane l covers cols 4l..4l+3.
__global__ __launch_bounds__(256)
void agg256_b(const ushort* __restrict__ h, const int* __restrict__ rp,
              const int* __restrict__ eidx, ushort* __restrict__ out, int nNodes) {
    int node = blockIdx.x * 4 + (threadIdx.x >> 6);
    if (node >= nNodes) return;
    int l = threadIdx.x & 63;
    int beg = rp[node], end = rp[node + 1];
    float a0 = 0.f, a1 = 0.f, a2 = 0.f, a3 = 0.f;
    int j = beg;
    for (; j + 1 < end; j += 2) {
        int s0 = eidx[j], s1 = eidx[j + 1];
        uint2 v0 = *reinterpret_cast<const uint2*>(h + (size_t)s0 * DH + l * 4);
        uint2 v1 = *reinterpret_cast<const uint2*>(h + (size_t)s1 * DH + l * 4);
        a0 += bf2f(v0.x & 0xffffu) + bf2f(v1.x & 0xffffu);
        a1 += bf2f(v0.x >> 16)     + bf2f(v1.x >> 16);
        a2 += bf2f(v0.y & 0xffffu) + bf2f(v1.y & 0xffffu);
        a3 += bf2f(v0.y >> 16)     + bf2f(v1.y >> 16);
    }
    if (j < end) {
        int s0 = eidx[j];
        uint2 v0 = *reinterpret_cast<const uint2*>(h + (size_t)s0 * DH + l * 4);
        a0 += bf2f(v0.x & 0xffffu);
        a1 += bf2f(v0.x >> 16);
        a2 += bf2f(v0.y & 0xffffu);
        a3 += bf2f(v0.y >> 16);
    }
    float inv = 1.0f / fmaxf((float)(end - beg), 1.0f);
    uint2 o;
    o.x = (uint)f2bf(a0 * inv) | ((uint)f2bf(a1 * inv) << 16);
    o.y = (uint)f2bf(a2 * inv) | ((uint)f2bf(a3 * inv) << 16);
    *reinterpret_cast<uint2*>(out + (size_t)node * DH + l * 4) = o;
}

// ================= dual MFMA GEMM ===========================================
template <int RELU, int OUTBF>
__global__ __launch_bounds__(256)
void gemm_dual(const ushort* __restrict__ A1, int K1, int S1, int str1,
               const ushort* __restrict__ A2, int K2, int S2, int str2,
               const ushort* __restrict__ B1p, const ushort* __restrict__ B2p,
               const float* __restrict__ bias, void* __restrict__ Cv,
               int M, int N, int NB, int NBW, int Cstride) {
    __shared__ ushort At[2][2048];

    const int tid = threadIdx.x;
    const int w = tid >> 6;
    const int l = tid & 63;
    const int m0 = blockIdx.x * 64;
    const int S = S1 + S2;

    f32x4 acc[4][4];
    #pragma unroll
    for (int m = 0; m < 4; ++m)
        #pragma unroll
        for (int i = 0; i < 4; ++i)
            acc[m][i] = f32x4{0.f, 0.f, 0.f, 0.f};

    auto stage = [&](int s, int buf) {
        const ushort* A; int str, Keff, ks;
        if (s < S1) { A = A1; str = str1; Keff = K1; ks = s; }
        else        { A = A2; str = str2; Keff = K2; ks = s - S1; }
        int r  = tid >> 2;
        int kc = tid & 3;
        int row = m0 + r;
        int k = ks * 32 + (kc << 3);
        U16B v;
        v.u4.x = v.u4.y = v.u4.z = v.u4.w = 0u;
        if (row < M && k < Keff) {
            const ushort* p = A + (size_t)row * str + k;
            v.u2[0] = *reinterpret_cast<const uint2*>(p);
            v.u2[1] = *reinterpret_cast<const uint2*>(p + 4);
            if (k + 8 > Keff) {
                #pragma unroll
                for (int j = 0; j < 8; ++j)
                    if (k + j >= Keff) v.us[j] = 0;
            }
        }
        int slot = ((r >> 4) << 6) | (r & 15) | (kc << 4);
        *reinterpret_cast<bhalf8*>(&At[buf][slot * 8]) = v.s8;
    };

    stage(0, 0);
    __syncthreads();

    for (int s = 0; s < S; ++s) {
        int buf = s & 1;
        if (s + 1 < S) stage(s + 1, buf ^ 1);

        const ushort* Bp; int ks;
        if (s < S1) { Bp = B1p; ks = s; }
        else        { Bp = B2p; ks = s - S1; }

        bhalf8 a[4];
        #pragma unroll
        for (int m = 0; m < 4; ++m)
            a[m] = *reinterpret_cast<bhalf8*>(&At[buf][((m << 6) | l) * 8]);

        #pragma unroll
        for (int i = 0; i < 4; ++i) {
            if (i < NBW) {
                int c = w * NBW + i;
                if (c < NB) {
                    bhalf8 b = *reinterpret_cast<const bhalf8*>(
                        Bp + ((size_t)(ks * NB + c) * 64 + l) * 8);
                    #pragma unroll
                    for (int m = 0; m < 4; ++m)
                        acc[m][i] = __builtin_amdgcn_mfma_f32_16x16x32_bf16(
                            a[m], b, acc[m][i], 0, 0, 0);
                }
            }
        }
        __syncthreads();
    }

    #pragma unroll
    for (int i = 0; i < 4; ++i) {
        if (i >= NBW) continue;
        int c = w * NBW + i;
        if (c >= NB) continue;
        int col = (c << 4) | (l & 15);
        if (col >= N) continue;
        float bb = bias[col];
        #pragma unroll
        for (int m = 0; m < 4; ++m) {
            #pragma unroll
            for (int e = 0; e < 4; ++e) {
                int row = m0 + (m << 4) + ((l >> 4) << 2) + e;
                if (row < M) {
                    float v = acc[m][i][e] + bb;
                    if (RELU) v = fmaxf(v, 0.0f);
                    if (OUTBF)
                        ((ushort*)Cv)[(size_t)row * Cstride + col] = f2bf(v);
                    else
                        ((float*)Cv)[(size_t)row * Cstride + col] = v;
                }
            }
        }
    }
}

// ================= log_softmax over 47 classes ==============================
__global__ void log_softmax_47(const float* __restrict__ z, float* __restrict__ out) {
    int row = blockIdx.x;
    int lane = threadIdx.x;
    float v = (lane < DOUT) ? z[(size_t)row * DOUT + lane] : -INFINITY;
    float m = v;
    #pragma unroll
    for (int off = 32; off; off >>= 1) m = fmaxf(m, __shfl_xor(m, off));
    float e = (lane < DOUT) ? expf(v - m) : 0.0f;
    float s = e;
    #pragma unroll
    for (int off = 32; off; off >>= 1) s += __shfl_xor(s, off);
    if (lane < DOUT) out[(size_t)row * DOUT + lane] = v - m - logf(s);
}

// ================= launch ====================================================
extern "C" void kernel_launch(void* const* d_in, const int* in_sizes, int n_in,
                              void* d_out, int out_size, void* d_ws, size_t ws_size,
                              hipStream_t stream) {
    const float* x   = (const float*)d_in[0];
    const int* e0s   = (const int*)d_in[1];
    const int* e0d   = (const int*)d_in[2];
    const int* e1s   = (const int*)d_in[3];
    const int* e1d   = (const int*)d_in[4];
    const int* e2s   = (const int*)d_in[5];
    const int* e2d   = (const int*)d_in[6];
    const float* Wl0 = (const float*)d_in[7];
    const float* Wr0 = (const float*)d_in[8];
    const float* b0  = (const float*)d_in[9];
    const float* Wl1 = (const float*)d_in[10];
    const float* Wr1 = (const float*)d_in[11];
    const float* b1  = (const float*)d_in[12];
    const float* Wl2 = (const float*)d_in[13];
    const float* Wr2 = (const float*)d_in[14];
    const float* b2  = (const float*)d_in[15];

    char* ws = (char*)d_ws;
    size_t off = 0;
    auto alloc = [&](size_t bytes) -> void* {
        void* p = ws + off;
        off += (bytes + 255) & ~(size_t)255;
        return p;
    };

    ushort* agg0b = (ushort*)alloc((size_t)NN1 * DIN * 2);
    ushort* h1    = (ushort*)alloc((size_t)NN1 * DH * 2);
    ushort* agg1b = (ushort*)alloc((size_t)NN2 * DH * 2);
    ushort* h2    = (ushort*)alloc((size_t)NN2 * DH * 2);
    ushort* agg2b = (ushort*)alloc((size_t)NN3 * DH * 2);
    float*  z     = (float*)alloc((size_t)NN3 * DOUT * 4);

    ushort* Bp0l = (ushort*)alloc((size_t)4 * 16 * 64 * 8 * 2);
    ushort* Bp0r = (ushort*)alloc((size_t)4 * 16 * 64 * 8 * 2);
    ushort* Bp1l = (ushort*)alloc((size_t)8 * 16 * 64 * 8 * 2);
    ushort* Bp1r = (ushort*)alloc((size_t)8 * 16 * 64 * 8 * 2);
    ushort* Bp2l = (ushort*)alloc((size_t)8 * 3 * 64 * 8 * 2);
    ushort* Bp2r = (ushort*)alloc((size_t)8 * 3 * 64 * 8 * 2);

    int* cntAll = (int*)alloc((size_t)(NN1 + NN2 + NN3) * 4);
    int* rp0   = (int*)alloc((size_t)(NN1 + 1) * 4);
    int* cur0  = (int*)alloc((size_t)NN1 * 4);
    int* eidx0 = (int*)alloc((size_t)EE0 * 4);
    int* rp1   = (int*)alloc((size_t)(NN2 + 1) * 4);
    int* cur1  = (int*)alloc((size_t)NN2 * 4);
    int* eidx1 = (int*)alloc((size_t)EE1 * 4);
    int* rp2   = (int*)alloc((size_t)(NN3 + 1) * 4);
    int* cur2  = (int*)alloc((size_t)NN3 * 4);
    int* eidx2 = (int*)alloc((size_t)EE2 * 4);
    int* part  = (int*)alloc(256 * 4);

    size_t fullNeed = (size_t)NN0 * DIN * 2 + 4096;
    bool big = (ws_size - off) >= fullNeed;
    int xRows = big ? NN0 : NN1;
    ushort* xb = (ushort*)alloc((size_t)xRows * DIN * 2 + 256);

    // ---- phase 1: zero hist counters; conv + 3 histograms fused ----
    hipMemsetAsync(cntAll, 0, (size_t)(NN1 + NN2 + NN3) * 4, stream);
    {
        long long n4 = (long long)xRows * DIN / 4;
        mega1<<<4000, 256, 0, stream>>>(x, xb, n4, e0d, e1d, e2d, cntAll);
    }

    // ---- phase 2: fused CSR scans + eidx ----
    scan1f<<<NBT, 256, 0, stream>>>(cntAll, part);
    scan2f<<<1, 128, 0, stream>>>(part);
    scan3f<<<NBT, 256, 0, stream>>>(cntAll, part, rp0, cur0, rp1, cur1, rp2, cur2);
    build_eidxf<<<928, 256, 0, stream>>>(e0s, e0d, e1s, e1d, e2s, e2d,
                                         cur0, cur1, cur2, eidx0, eidx1, eidx2);

    // ---- weight packing (tiny) ----
    pack_all<<<432, 64, 0, stream>>>(Wl0, Wr0, Wl1, Wr1, Wl2, Wr2,
                                     Bp0l, Bp0r, Bp1l, Bp1r, Bp2l, Bp2r);

    // ---- layer 0 ----
    if (big)
        agg100_b<<<(NN1 + 3) / 4, 256, 0, stream>>>(xb, rp0, eidx0, agg0b, NN1);
    else
        agg100_f<<<(NN1 + 3) / 4, 256, 0, stream>>>(x, rp0, eidx0, agg0b, NN1);
    gemm_dual<1, 1><<<(NN1 + 63) / 64, 256, 0, stream>>>(
        agg0b, DIN, 4, DIN, xb, DIN, 4, DIN, Bp0l, Bp0r, b0, h1,
        NN1, DH, 16, 4, DH);

    // ---- layer 1 ----
    agg256_b<<<(NN2 + 3) / 4, 256, 0, stream>>>(h1, rp1, eidx1, agg1b, NN2);
    gemm_dual<1, 1><<<(NN2 + 63) / 64, 256, 0, stream>>>(
        agg1b, DH, 8, DH, h1, DH, 8, DH, Bp1l, Bp1r, b1, h2,
        NN2, DH, 16, 4, DH);

    // ---- layer 2 ----
    agg256_b<<<(NN3 + 3) / 4, 256, 0, stream>>>(h2, rp2, eidx2, agg2b, NN3);
    gemm_dual<0, 0><<<(NN3 + 63) / 64, 256, 0, stream>>>(
        agg2b, DH, 8, DH, h2, DH, 8, DH, Bp2l, Bp2r, b2, z,
        NN3, DOUT, 3, 1, DOUT);

    // ---- log_softmax ----
    log_softmax_47<<<NN3, 64, 0, stream>>>(z, (float*)d_out);
}